// Round 9
// baseline (1683.343 us; speedup 1.0000x reference)
//
#include <hip/hip_runtime.h>
#include <math.h>

#define H 512
#define V 32000
#define NVB 250     // vocab blocks (32000 / 128)

typedef unsigned short ushort_t;
typedef __attribute__((ext_vector_type(8))) short short8;
typedef __attribute__((ext_vector_type(4))) float f32x4;

// ---- bf16 split helpers (bit-level RNE) ----
__device__ __forceinline__ unsigned short f2bf(float x) {
    unsigned int u; __builtin_memcpy(&u, &x, 4);
    unsigned int r = (u + 0x7fffu + ((u >> 16) & 1u)) >> 16;
    return (unsigned short)r;
}
__device__ __forceinline__ float bfu2f(unsigned short h) {
    unsigned int u = ((unsigned int)h) << 16;
    float f; __builtin_memcpy(&f, &u, 4);
    return f;
}

__device__ __forceinline__ void t2_insert(float& m1, int& c1, float& m2, int& c2,
                                          float v, int idx) {
    if (v > m1 || (v == m1 && idx < c1)) { m2 = m1; c2 = c1; m1 = v; c1 = idx; }
    else if (v > m2 || (v == m2 && idx < c2)) { m2 = v; c2 = idx; }
}

// async global->LDS, 16 bytes/lane; LDS dest = wave-uniform base + lane*16;
// global SOURCE is per-lane (guide m173) - we exploit that for channel spread.
__device__ __forceinline__ void gl16(const void* g, void* l) {
    __builtin_amdgcn_global_load_lds(
        (const __attribute__((address_space(1))) void*)g,
        (__attribute__((address_space(3))) void*)l,
        16, 0, 0);
}

// ---------------------------------------------------------------------------
// Kernel 1: ts = tanh(A @ W_em + b_em)
// ---------------------------------------------------------------------------
__global__ __launch_bounds__(256) void k_emstate(
    const float* __restrict__ y_hidden, const float* __restrict__ y_null,
    const float* __restrict__ W, const float* __restrict__ bias,
    float* __restrict__ ts)
{
    const int NR = 2049;
    __shared__ float As[16][64];
    __shared__ float Bs[16][64];
    int rb = blockIdx.y, cb = blockIdx.x;
    int row0 = rb * 64, col0 = cb * 64;
    int tid = threadIdx.x;
    int tr = tid >> 4, tc = tid & 15;
    float acc[4][4] = {};
    for (int k0 = 0; k0 < H; k0 += 16) {
        {
            int r = tid >> 2;
            int kk = (tid & 3) << 2;
            int row = row0 + r;
            float4 v = make_float4(0.f, 0.f, 0.f, 0.f);
            if (row < 2048)       v = *(const float4*)&y_hidden[row * H + k0 + kk];
            else if (row == 2048) v = *(const float4*)&y_null[k0 + kk];
            As[kk + 0][r] = v.x; As[kk + 1][r] = v.y;
            As[kk + 2][r] = v.z; As[kk + 3][r] = v.w;
            int bk = tid >> 4, bc = (tid & 15) << 2;
            *(float4*)&Bs[bk][bc] = *(const float4*)&W[(k0 + bk) * H + col0 + bc];
        }
        __syncthreads();
#pragma unroll
        for (int kk = 0; kk < 16; ++kk) {
            float4 a = *(float4*)&As[kk][tr * 4];
            float4 b = *(float4*)&Bs[kk][tc * 4];
            float av[4] = {a.x, a.y, a.z, a.w};
            float bv[4] = {b.x, b.y, b.z, b.w};
#pragma unroll
            for (int i = 0; i < 4; i++)
#pragma unroll
                for (int j = 0; j < 4; j++) acc[i][j] += av[i] * bv[j];
        }
        __syncthreads();
    }
#pragma unroll
    for (int i = 0; i < 4; i++) {
        int row = row0 + tr * 4 + i;
        if (row >= NR) break;
#pragma unroll
        for (int j = 0; j < 4; j++) {
            int col = col0 + tc * 4 + j;
            ts[(size_t)row * H + col] = tanhf(acc[i][j] + bias[col]);
        }
    }
}

// ---------------------------------------------------------------------------
// Pack A (f32 [rows][512]) -> LANE-MAJOR fragment blocks, bf16 hi/lo.
// Element (n16, k32, lane l) at ushort offset n16*8192 + l*128 + k32*8.
// Lane l holds elems (m=n16*16+(l&15), k=k32*32+(l>>4)*8 .. +7).
// Lane-major => one gl16's 64 lanes are strided 256 B apart (span 16 KB,
// 64 distinct cache lines) instead of one contiguous 1 KB region.
// ---------------------------------------------------------------------------
__global__ __launch_bounds__(256) void k_packA(
    const float* __restrict__ A, int nvalid, int nb16,
    ushort_t* __restrict__ Ph, ushort_t* __restrict__ Pl)
{
    int c = blockIdx.x * 256 + threadIdx.x;
    if (c >= nb16 * 1024) return;
    int n16 = c >> 10, rem = c & 1023, k32 = rem >> 6, l = rem & 63;
    int m = n16 * 16 + (l & 15);
    int k = k32 * 32 + (l >> 4) * 8;
    float v[8];
    if (m < nvalid) {
        *(float4*)&v[0] = *(const float4*)&A[(size_t)m * H + k];
        *(float4*)&v[4] = *(const float4*)&A[(size_t)m * H + k + 4];
    } else {
#pragma unroll
        for (int j = 0; j < 8; ++j) v[j] = 0.f;
    }
    unsigned int hh[4], lo[4];
#pragma unroll
    for (int p = 0; p < 4; ++p) {
        unsigned short h0 = f2bf(v[2 * p]), h1 = f2bf(v[2 * p + 1]);
        hh[p] = (unsigned int)h0 | ((unsigned int)h1 << 16);
        unsigned short l0 = f2bf(v[2 * p] - bfu2f(h0));
        unsigned short l1 = f2bf(v[2 * p + 1] - bfu2f(h1));
        lo[p] = (unsigned int)l0 | ((unsigned int)l1 << 16);
    }
    size_t o = (size_t)n16 * 8192 + (size_t)l * 128 + k32 * 8;
    *(uint4*)&Ph[o] = make_uint4(hh[0], hh[1], hh[2], hh[3]);
    *(uint4*)&Pl[o] = make_uint4(lo[0], lo[1], lo[2], lo[3]);
}

// ---------------------------------------------------------------------------
// Pack W (f32 [512][32000], k-major) -> LANE-MAJOR fragment blocks (n as m).
// ---------------------------------------------------------------------------
__global__ __launch_bounds__(256) void k_packW(
    const float* __restrict__ W,
    ushort_t* __restrict__ Ph, ushort_t* __restrict__ Pl)
{
    int c = blockIdx.x * 256 + threadIdx.x;
    int n16 = c >> 10, rem = c & 1023, k32 = rem >> 6, l = rem & 63;
    int n = n16 * 16 + (l & 15);
    int k = k32 * 32 + (l >> 4) * 8;
    float v[8];
#pragma unroll
    for (int j = 0; j < 8; ++j) v[j] = W[(size_t)(k + j) * V + n];
    unsigned int hh[4], lo[4];
#pragma unroll
    for (int p = 0; p < 4; ++p) {
        unsigned short h0 = f2bf(v[2 * p]), h1 = f2bf(v[2 * p + 1]);
        hh[p] = (unsigned int)h0 | ((unsigned int)h1 << 16);
        unsigned short l0 = f2bf(v[2 * p] - bfu2f(h0));
        unsigned short l1 = f2bf(v[2 * p + 1] - bfu2f(h1));
        lo[p] = (unsigned int)l0 | ((unsigned int)l1 << 16);
    }
    size_t o = (size_t)n16 * 8192 + (size_t)l * 128 + k32 * 8;
    *(uint4*)&Ph[o] = make_uint4(hh[0], hh[1], hh[2], hh[3]);
    *(uint4*)&Pl[o] = make_uint4(lo[0], lo[1], lo[2], lo[3]);
}

// ---------------------------------------------------------------------------
// Kernel 2: split-bf16 MFMA GEMM, 256x256 tile, 8 waves, counted-vmcnt
// 2-deep gl16 pipeline + LANE-MAJOR (channel-spread) operand layout.
//
// Round-8 post-mortem: counted-vmcnt (16 outstanding/wave) measured
// IDENTICAL (833us, MfmaUtil 10.05%) -> in-flight depth is not the limit.
// Seven structures, one time. The discriminator is m97 (guide): same chip,
// same gl16-w16, same drain-per-K-step, but ~23 B/cy/CU staging vs our
// 2-4. Its gl16 sources are per-lane SCATTERED (row-major tiles, 8KB row
// stride -> 64 lanes span ~1MB, ~64 L2/HBM channels); ours were one
// CONTIGUOUS 1KB (16 adjacent lines, few channel slots), and lockstep
// blocks hammer the same narrow 64KB window per epoch -> channel
// serialization. Fits all 7 rounds incl. r3/r4 (contiguous across lanes).
//
// Fix: lane-major repack. gl16 lane stride = 256 B -> each request spans
// 16 KB / 64 lines; block epoch spans 512 KB (was 64 KB). Each 64-B line
// carries 4 consecutive chunks (4x line-fetch amortization). LDS contents
// after gl16 are BIT-IDENTICAL to before (index algebra verified) ->
// ds_reads/MFMAs/epilogue untouched.
// ---------------------------------------------------------------------------
template<bool TOP2>
__global__ __launch_bounds__(512, 2) void k_gemm(
    int nrb,
    const ushort_t* __restrict__ Ah, const ushort_t* __restrict__ Al,
    const ushort_t* __restrict__ Bh, const ushort_t* __restrict__ Bl,
    const float* __restrict__ bias,
    float* __restrict__ pL,
    float* __restrict__ pM1, float* __restrict__ pM2,
    int* __restrict__ pI1, int* __restrict__ pI2)
{
    // ---- XCD-aware block remap: rb-halves x vb-quarters (125 = 32+31+31+31)
    const int id  = blockIdx.x;
    const int xcd = id & 7;
    const int seq = id >> 3;
    const int rbg = xcd >> 2;
    const int vbg = xcd & 3;
    const int g0  = (nrb + 1) >> 1;
    const int nrbg = rbg ? (nrb - g0) : g0;
    const int vbl = seq / nrbg;
    const int rbl = seq - vbl * nrbg;
    const int vbsz = (vbg == 0) ? 32 : 31;
    if (vbl >= vbsz) return;
    const int rb = rbg ? (g0 + rbl) : rbl;
    const int vb = ((vbg == 0) ? 0 : (1 + 31 * vbg)) + vbl;   // bases 0,32,63,94

    // 2 buffers x 4 arrays x 16 KB = 128 KB
    __shared__ __attribute__((aligned(16))) ushort_t AshB[2][16 * 512];
    __shared__ __attribute__((aligned(16))) ushort_t AslB[2][16 * 512];
    __shared__ __attribute__((aligned(16))) ushort_t BshB[2][16 * 512];
    __shared__ __attribute__((aligned(16))) ushort_t BslB[2][16 * 512];
    __shared__ float sc_s[256][4];
    __shared__ float sc_m1[256][4], sc_m2[256][4];
    __shared__ int   sc_c1[256][4], sc_c2[256][4];

    const int tid = threadIdx.x;
    const int lane = tid & 63, w = tid >> 6;
    const int wy = w >> 2, wx = w & 3;     // wave grid 2x4, each wave 128x64

    f32x4 acc[8][4];
#pragma unroll
    for (int i = 0; i < 8; ++i)
#pragma unroll
        for (int j = 0; j < 4; ++j)
#pragma unroll
            for (int r = 0; r < 4; ++r) acc[i][j][r] = 0.f;

    // staging: wave pair (w>>1) owns one array; halves by (w&1). 8 gl16/wave.
    // Lane-major layout: element (n16b, k32, lane) at ushort offset
    //   n16b*8192 + lane*128 + k32*8.
    const ushort_t* gsrc = (w < 2) ? Ah : (w < 4) ? Al : (w < 6) ? Bh : Bl;
    ushort_t* base0 = (w < 2) ? AshB[0] : (w < 4) ? AslB[0] : (w < 6) ? BshB[0] : BslB[0];
    ushort_t* base1 = (w < 2) ? AshB[1] : (w < 4) ? AslB[1] : (w < 6) ? BshB[1] : BslB[1];
    const int half = (w & 1) * 8;
    ushort_t* ldb0 = base0 + half * 512;
    ushort_t* ldb1 = base1 + half * 512;
    const size_t n16base = (size_t)(((w < 4) ? rb : vb) * 16 + half);
    // per-lane source base: lanes strided 128 ushorts = 256 B apart
    const ushort_t* lane_src = gsrc + n16base * 8192 + (size_t)lane * 128;

#define STAGE(DST, IT)                                                   \
    _Pragma("unroll")                                                    \
    for (int mb = 0; mb < 8; ++mb)                                       \
        gl16(lane_src + (size_t)mb * 8192 + (IT) * 8, (DST) + mb * 512);

// WIMM: 0x0F78 = vmcnt(8) (next chunk's 8 gl16 stay in flight),
//       0x0F70 = vmcnt(0) (final drain).  expcnt/lgkmcnt = no-wait.
#define STEPX(BUF, IT, DOPREF, WIMM)                                     \
{                                                                        \
    __builtin_amdgcn_s_waitcnt(WIMM);    /* my chunk IT landed */        \
    __builtin_amdgcn_s_barrier();        /* all waves' chunk IT ready */ \
    __builtin_amdgcn_sched_barrier(0);                                   \
    const ushort_t* cAh = AshB[BUF];                                     \
    const ushort_t* cAl = AslB[BUF];                                     \
    const ushort_t* cBh = BshB[BUF];                                     \
    const ushort_t* cBl = BslB[BUF];                                     \
    short8 bhf[4], blf[4];                                               \
    _Pragma("unroll")                                                    \
    for (int j = 0; j < 4; ++j) {                                        \
        bhf[j] = *(const short8*)&cBh[((wx * 4 + j) << 9) + (lane << 3)]; \
        blf[j] = *(const short8*)&cBl[((wx * 4 + j) << 9) + (lane << 3)]; \
    }                                                                    \
    _Pragma("unroll")                                                    \
    for (int i = 0; i < 8; ++i) {                                        \
        short8 ah = *(const short8*)&cAh[((wy * 8 + i) << 9) + (lane << 3)]; \
        short8 al = *(const short8*)&cAl[((wy * 8 + i) << 9) + (lane << 3)]; \
        _Pragma("unroll")                                                \
        for (int j = 0; j < 4; ++j) {                                    \
            acc[i][j] = __builtin_amdgcn_mfma_f32_16x16x32_bf16(ah, bhf[j], acc[i][j], 0, 0, 0); \
            acc[i][j] = __builtin_amdgcn_mfma_f32_16x16x32_bf16(ah, blf[j], acc[i][j], 0, 0, 0); \
            acc[i][j] = __builtin_amdgcn_mfma_f32_16x16x32_bf16(al, bhf[j], acc[i][j], 0, 0, 0); \
        }                                                                \
    }                                                                    \
    __builtin_amdgcn_sched_barrier(0);                                   \
    __builtin_amdgcn_s_barrier();        /* all done reading buf BUF */  \
    if (DOPREF) { STAGE((BUF) ? ldb1 : ldb0, (IT) + 2) }                 \
}

    // prologue: chunks 0,1 in flight (no drain)
    STAGE(ldb0, 0)
    STAGE(ldb1, 1)

#pragma unroll 1
    for (int it = 0; it < 14; it += 2) {
        STEPX(0, it,     1, 0x0F78)      // consume even chunk, issue it+2
        STEPX(1, it + 1, 1, 0x0F78)      // consume odd chunk,  issue it+3
    }
    STEPX(0, 14, 0, 0x0F78)              // c15 still in flight
    STEPX(1, 15, 0, 0x0F70)              // final drain
#undef STAGE
#undef STEPX

    // ---- epilogue: sumexp (+ top-2) per row; emit per-128-col blocks ----
    // C/D layout (16x16x32): col = lane&15, row = (lane>>4)*4 + reg.
    float b4[4];
#pragma unroll
    for (int j = 0; j < 4; ++j) b4[j] = bias[vb * 256 + wx * 64 + j * 16 + (lane & 15)];
    const int colbase = vb * 256 + wx * 64 + (lane & 15);

#pragma unroll
    for (int i = 0; i < 8; ++i) {
#pragma unroll
        for (int r = 0; r < 4; ++r) {
            float s = 0.f;
            float m1 = -3e38f, m2 = -3e38f; int c1 = 0x7fffffff, c2 = 0x7fffffff;
#pragma unroll
            for (int j = 0; j < 4; ++j) {
                float v = acc[i][j][r] + b4[j];
                s += __expf(v);
                if (TOP2) t2_insert(m1, c1, m2, c2, v, colbase + j * 16);
            }
            for (int st = 1; st < 16; st <<= 1) {
                s += __shfl_xor(s, st, 64);
                if (TOP2) {
                    float om1 = __shfl_xor(m1, st, 64); int oc1 = __shfl_xor(c1, st, 64);
                    float om2 = __shfl_xor(m2, st, 64); int oc2 = __shfl_xor(c2, st, 64);
                    t2_insert(m1, c1, m2, c2, om1, oc1);
                    t2_insert(m1, c1, m2, c2, om2, oc2);
                }
            }
            if ((lane & 15) == 0) {
                int rowLoc = wy * 128 + i * 16 + (lane >> 4) * 4 + r;
                sc_s[rowLoc][wx] = s;
                if (TOP2) {
                    sc_m1[rowLoc][wx] = m1; sc_c1[rowLoc][wx] = c1;
                    sc_m2[rowLoc][wx] = m2; sc_c2[rowLoc][wx] = c2;
                }
            }
        }
    }
    __syncthreads();
    if (tid < 256) {
        int rowG = rb * 256 + tid;
        // col-halves {wx 0,1} -> vb*2, {wx 2,3} -> vb*2+1 (128 cols each)
        pL[(size_t)rowG * NVB + vb * 2 + 0] = sc_s[tid][0] + sc_s[tid][1];
        pL[(size_t)rowG * NVB + vb * 2 + 1] = sc_s[tid][2] + sc_s[tid][3];
        if (TOP2) {
#pragma unroll
            for (int h = 0; h < 2; ++h) {
                int g0i = h * 2, g1i = h * 2 + 1;
                float m1 = sc_m1[tid][g0i]; int c1 = sc_c1[tid][g0i];
                float m2 = sc_m2[tid][g0i]; int c2 = sc_c2[tid][g0i];
                t2_insert(m1, c1, m2, c2, sc_m1[tid][g1i], sc_c1[tid][g1i]);
                t2_insert(m1, c1, m2, c2, sc_m2[tid][g1i], sc_c2[tid][g1i]);
                pM1[(size_t)rowG * NVB + vb * 2 + h] = m1;
                pM2[(size_t)rowG * NVB + vb * 2 + h] = m2;
                pI1[(size_t)rowG * NVB + vb * 2 + h] = c1;
                pI2[(size_t)rowG * NVB + vb * 2 + h] = c2;
            }
        }
    }
}

// ---------------------------------------------------------------------------
// Kernel 3a: combine source partials -> L (denominator only)
// ---------------------------------------------------------------------------
__global__ __launch_bounds__(256) void k_combine_src(
    const float* __restrict__ pL, int nrows, float* __restrict__ L)
{
    int w = threadIdx.x >> 6, ll = threadIdx.x & 63;
    int row = blockIdx.x * 4 + w;
    if (row >= nrows) return;
    const float* p = &pL[(size_t)row * NVB];
    float s = 0.f;
    for (int vb = ll; vb < NVB; vb += 64) s += p[vb];
    for (int st = 1; st < 64; st <<= 1) s += __shfl_xor(s, st, 64);
    if (ll == 0) L[row] = s;
}

// ---------------------------------------------------------------------------
// Kernel 3b: combine target partials -> L + global approx top-2 candidates
// ---------------------------------------------------------------------------
__global__ __launch_bounds__(256) void k_combine_tgt(
    const float* __restrict__ pL,
    const float* __restrict__ pM1, const float* __restrict__ pM2,
    const int* __restrict__ pI1, const int* __restrict__ pI2,
    float* __restrict__ L, int* __restrict__ C0, int* __restrict__ C1)
{
    int w = threadIdx.x >> 6, ll = threadIdx.x & 63;
    int row = blockIdx.x * 4 + w;
    if (row >= 2048) return;
    size_t base = (size_t)row * NVB;
    float s = 0.f;
    float m1 = -3e38f, m2 = -3e38f; int c1 = 0x7fffffff, c2 = 0x7fffffff;
    for (int vb = ll; vb < NVB; vb += 64) {
        s += pL[base + vb];
        t2_insert(m1, c1, m2, c2, pM1[base + vb], pI1[base + vb]);
        t2_insert(m1, c1, m2, c2, pM2[base + vb], pI2[base + vb]);
    }
    for (int st = 1; st < 64; st <<= 1) {
        s += __shfl_xor(s, st, 64);
        float om1 = __shfl_xor(m1, st, 64); int oc1 = __shfl_xor(c1, st, 64);
        float om2 = __shfl_xor(m2, st, 64); int oc2 = __shfl_xor(c2, st, 64);
        t2_insert(m1, c1, m2, c2, om1, oc1);
        t2_insert(m1, c1, m2, c2, om2, oc2);
    }
    if (ll == 0) { L[row] = s; C0[row] = c1; C1[row] = c2; }
}

// ---------------------------------------------------------------------------
// Kernel 4: emission output (exact f32 dot for gathered columns)
// ---------------------------------------------------------------------------
__global__ __launch_bounds__(256) void k_emission(
    const float* __restrict__ ts, const float* __restrict__ W_sv,
    const float* __restrict__ b_sv, const int* __restrict__ sources,
    const float* __restrict__ L, float* __restrict__ out)
{
    __shared__ float wcol[H];
    __shared__ float sbias;
    int b = blockIdx.y, tx = blockIdx.x;
    int tid = threadIdx.x;
    int s = sources[b * 64 + tx];
    wcol[tid]       = W_sv[(size_t)tid * V + s];
    wcol[tid + 256] = W_sv[(size_t)(tid + 256) * V + s];
    if (tid == 0) sbias = b_sv[s];
    __syncthreads();
    int w = tid >> 6, ll = tid & 63;
    for (int r = w; r <= 64; r += 4) {
        int row = (r < 64) ? (b * 64 + r) : 2048;
        const float* a = &ts[(size_t)row * H];
        float sum = 0.f;
#pragma unroll
        for (int j = 0; j < 8; ++j) sum += a[ll * 8 + j] * wcol[ll * 8 + j];
        for (int m2 = 1; m2 < 64; m2 <<= 1) sum += __shfl_xor(sum, m2, 64);
        float prob = __expf(sum + sbias) / L[row];
        if (r < 64) {
            if (ll == 0) out[b * 8192 + r * 64 + tx] = prob;
        } else {
            out[b * 8192 + (64 + ll) * 64 + tx] = prob;
        }
    }
}

// ---------------------------------------------------------------------------
// Kernel 5: target epilogue — exact recompute of token + 2 argmax candidates
// ---------------------------------------------------------------------------
__global__ __launch_bounds__(256) void k_target_final(
    const float* __restrict__ tstate,
    const float* __restrict__ W_tv, const float* __restrict__ b_tv,
    const int* __restrict__ targets, const int* __restrict__ tlen,
    const float* __restrict__ L, const int* __restrict__ C0,
    const int* __restrict__ C1,
    float* __restrict__ out_exp, float* __restrict__ out_log,
    float* __restrict__ out_pred)
{
    int w = threadIdx.x >> 6, ll = threadIdx.x & 63;
    int row = blockIdx.x * 4 + w;
    if (row >= 2048) return;
    int tok = targets[row], a0 = C0[row], a1 = C1[row];
    const float* a = &tstate[(size_t)row * H];
    float s0 = 0.f, s1 = 0.f, s2 = 0.f;
#pragma unroll
    for (int j = 0; j < 8; ++j) {
        int k = ll * 8 + j;
        float av = a[k];
        const float* wr = &W_tv[(size_t)k * V];
        s0 += av * wr[tok]; s1 += av * wr[a0]; s2 += av * wr[a1];
    }
    for (int st = 1; st < 64; st <<= 1) {
        s0 += __shfl_xor(s0, st, 64);
        s1 += __shfl_xor(s1, st, 64);
        s2 += __shfl_xor(s2, st, 64);
    }
    if (ll == 0) {
        float ltok = s0 + b_tv[tok];
        float v0 = s1 + b_tv[a0], v1 = s2 + b_tv[a1];
        int pred = (v1 > v0 || (v1 == v0 && a1 < a0)) ? a1 : a0;
        float Li = L[row];
        int bb = row >> 6, t = row & 63;
        int mask = (t < tlen[bb]) ? 1 : 0;
        float prob = __expf(ltok) / Li;
        out_exp[row]  = mask ? prob : 0.f;
        out_log[row]  = mask ? (ltok - __logf(Li)) : 0.f;
        out_pred[row] = (float)pred;
    }
}

// ---------------------------------------------------------------------------
extern "C" void kernel_launch(void* const* d_in, const int* in_sizes, int n_in,
                              void* d_out, int out_size, void* d_ws, size_t ws_size,
                              hipStream_t stream)
{
    const float* y_hidden = (const float*)d_in[0];
    const float* y_null   = (const float*)d_in[1];
    const float* tstate   = (const float*)d_in[2];
    const float* W_em     = (const float*)d_in[3];
    const float* b_em     = (const float*)d_in[4];
    const float* W_sv     = (const float*)d_in[5];
    const float* b_sv     = (const float*)d_in[6];
    const float* W_tv     = (const float*)d_in[7];
    const float* b_tv     = (const float*)d_in[8];
    const int*   sources  = (const int*)d_in[9];
    const int*   targets  = (const int*)d_in[10];
    const int*   tlen     = (const int*)d_in[11];

    float* out = (float*)d_out;
    float* out_em   = out;
    float* out_exp  = out + 262144;
    float* out_log  = out + 264192;
    float* out_pred = out + 266240;

    // ---- workspace layout (float units) ----
    float* ws = (float*)d_ws;
    size_t off = 0;
    float*    ts    = ws + off; off += (size_t)2176 * H;
    ushort_t* tsPh  = (ushort_t*)(ws + off); off += (size_t)2304 * H / 2;  // 144 n16-blocks
    ushort_t* tsPl  = (ushort_t*)(ws + off); off += (size_t)2304 * H / 2;
    ushort_t* ttPh  = (ushort_t*)(ws + off); off += (size_t)2048 * H / 2;
    ushort_t* ttPl  = (ushort_t*)(ws + off); off += (size_t)2048 * H / 2;
    ushort_t* Wh    = (ushort_t*)(ws + off); off += (size_t)V * H / 2;   // reused
    ushort_t* Wl    = (ushort_t*)(ws + off); off += (size_t)V * H / 2;
    float* pL0  = ws + off; off += (size_t)2304 * NVB;
    float* pL1  = ws + off; off += (size_t)2048 * NVB;
    float* pM1a = ws + off; off += (size_t)2048 * NVB;
    float* pM1b = ws + off; off += (size_t)2048 * NVB;
    int*   pI1a = (int*)(ws + off); off += (size_t)2048 * NVB;
    int*   pI1b = (int*)(ws + off); off += (size_t)2048 * NVB;
    float* L0   = ws + off; off += 2176;
    float* L1   = ws + off; off += 2048;
    int*   C0   = (int*)(ws + off); off += 2048;
    int*   C1   = (int*)(ws + off); off += 2048;

    // 1) hidden-state transform
    k_emstate<<<dim3(8, 33), 256, 0, stream>>>(y_hidden, y_null, W_em, b_em, ts);

    // 1b) pack A-side operands into lane-major fragment-block bf16 hi/lo
    //     src padded to 144 n16-blocks (2304 rows) for 256-row tiling
    k_packA<<<(144 * 1024) / 256, 256, 0, stream>>>(ts, 2049, 144, tsPh, tsPl);
    k_packA<<<(128 * 1024) / 256, 256, 0, stream>>>(tstate, 2048, 128, ttPh, ttPl);

    // 2a) source side: pack W_sv, GEMM (256x256 tiles; nrb=9 -> halves 5/4;
    //     per-XCD max 5*32 = 160 -> grid 8*160)
    k_packW<<<(2000 * 1024) / 256, 256, 0, stream>>>(W_sv, Wh, Wl);
    k_gemm<false><<<dim3(8 * 160), 512, 0, stream>>>(
        9, tsPh, tsPl, Wh, Wl, b_sv, pL0, nullptr, nullptr, nullptr, nullptr);

    // 2b) target side: pack W_tv (buffer reuse, stream-ordered), GEMM
    //     (nrb=8 -> halves 4/4; per-XCD max 4*32 = 128 -> grid 8*128)
    k_packW<<<(2000 * 1024) / 256, 256, 0, stream>>>(W_tv, Wh, Wl);
    k_gemm<true><<<dim3(8 * 128), 512, 0, stream>>>(
        8, ttPh, ttPl, Wh, Wl, b_tv, pL1, pM1a, pM1b, pI1a, pI1b);

    // 3) combine partials
    k_combine_src<<<(2049 + 3) / 4, 256, 0, stream>>>(pL0, 2049, L0);
    k_combine_tgt<<<2048 / 4, 256, 0, stream>>>(pL1, pM1a, pM1b, pI1a, pI1b,
                                                L1, C0, C1);

    // 4) emission gather (exact f32 logits)
    k_emission<<<dim3(64, 32), 256, 0, stream>>>(ts, W_sv, b_sv, sources, L0, out_em);

    // 5) target epilogue with exact candidate recompute
    k_target_final<<<2048 / 4, 256, 0, stream>>>(tstate, W_tv, b_tv, targets, tlen,
                                                 L1, C0, C1,
                                                 out_exp, out_log, out_pred);
}

// Round 10
// 1513.367 us; speedup vs baseline: 1.1123x; 1.1123x over previous
//
#include <hip/hip_runtime.h>
#include <math.h>

#define H 512
#define V 32000
#define NVB 250     // vocab blocks (32000 / 128)

typedef unsigned short ushort_t;
typedef __attribute__((ext_vector_type(8))) short short8;
typedef __attribute__((ext_vector_type(4))) float f32x4;

// ---- bf16 split helpers (bit-level RNE) ----
__device__ __forceinline__ unsigned short f2bf(float x) {
    unsigned int u; __builtin_memcpy(&u, &x, 4);
    unsigned int r = (u + 0x7fffu + ((u >> 16) & 1u)) >> 16;
    return (unsigned short)r;
}
__device__ __forceinline__ float bfu2f(unsigned short h) {
    unsigned int u = ((unsigned int)h) << 16;
    float f; __builtin_memcpy(&f, &u, 4);
    return f;
}

__device__ __forceinline__ void t2_insert(float& m1, int& c1, float& m2, int& c2,
                                          float v, int idx) {
    if (v > m1 || (v == m1 && idx < c1)) { m2 = m1; c2 = c1; m1 = v; c1 = idx; }
    else if (v > m2 || (v == m2 && idx < c2)) { m2 = v; c2 = idx; }
}

// async global->LDS, 16 bytes/lane; LDS dest = wave-uniform base + lane*16
__device__ __forceinline__ void gl16(const void* g, void* l) {
    __builtin_amdgcn_global_load_lds(
        (const __attribute__((address_space(1))) void*)g,
        (__attribute__((address_space(3))) void*)l,
        16, 0, 0);
}

// ---------------------------------------------------------------------------
// Kernel 1: ts = tanh(A @ W_em + b_em)
// ---------------------------------------------------------------------------
__global__ __launch_bounds__(256) void k_emstate(
    const float* __restrict__ y_hidden, const float* __restrict__ y_null,
    const float* __restrict__ W, const float* __restrict__ bias,
    float* __restrict__ ts)
{
    const int NR = 2049;
    __shared__ float As[16][64];
    __shared__ float Bs[16][64];
    int rb = blockIdx.y, cb = blockIdx.x;
    int row0 = rb * 64, col0 = cb * 64;
    int tid = threadIdx.x;
    int tr = tid >> 4, tc = tid & 15;
    float acc[4][4] = {};
    for (int k0 = 0; k0 < H; k0 += 16) {
        {
            int r = tid >> 2;
            int kk = (tid & 3) << 2;
            int row = row0 + r;
            float4 v = make_float4(0.f, 0.f, 0.f, 0.f);
            if (row < 2048)       v = *(const float4*)&y_hidden[row * H + k0 + kk];
            else if (row == 2048) v = *(const float4*)&y_null[k0 + kk];
            As[kk + 0][r] = v.x; As[kk + 1][r] = v.y;
            As[kk + 2][r] = v.z; As[kk + 3][r] = v.w;
            int bk = tid >> 4, bc = (tid & 15) << 2;
            *(float4*)&Bs[bk][bc] = *(const float4*)&W[(k0 + bk) * H + col0 + bc];
        }
        __syncthreads();
#pragma unroll
        for (int kk = 0; kk < 16; ++kk) {
            float4 a = *(float4*)&As[kk][tr * 4];
            float4 b = *(float4*)&Bs[kk][tc * 4];
            float av[4] = {a.x, a.y, a.z, a.w};
            float bv[4] = {b.x, b.y, b.z, b.w};
#pragma unroll
            for (int i = 0; i < 4; i++)
#pragma unroll
                for (int j = 0; j < 4; j++) acc[i][j] += av[i] * bv[j];
        }
        __syncthreads();
    }
#pragma unroll
    for (int i = 0; i < 4; i++) {
        int row = row0 + tr * 4 + i;
        if (row >= NR) break;
#pragma unroll
        for (int j = 0; j < 4; j++) {
            int col = col0 + tc * 4 + j;
            ts[(size_t)row * H + col] = tanhf(acc[i][j] + bias[col]);
        }
    }
}

// ---------------------------------------------------------------------------
// Pack A (f32 [rows][512]) -> fragment-block bf16 hi/lo (r8 block-contiguous
// layout; r9's lane-major was measured WORSE and is reverted).
// Block (n16,k32) = 1 KB at offset (n16*16+k32)*512 ushorts; lane l holds
// elems (m=n16*16+(l&15), k=k32*32+(l>>4)*8 .. +7), 16 B contiguous.
// ---------------------------------------------------------------------------
__global__ __launch_bounds__(256) void k_packA(
    const float* __restrict__ A, int nvalid, int nb16,
    ushort_t* __restrict__ Ph, ushort_t* __restrict__ Pl)
{
    int c = blockIdx.x * 256 + threadIdx.x;
    if (c >= nb16 * 1024) return;
    int n16 = c >> 10, rem = c & 1023, k32 = rem >> 6, l = rem & 63;
    int m = n16 * 16 + (l & 15);
    int k = k32 * 32 + (l >> 4) * 8;
    float v[8];
    if (m < nvalid) {
        *(float4*)&v[0] = *(const float4*)&A[(size_t)m * H + k];
        *(float4*)&v[4] = *(const float4*)&A[(size_t)m * H + k + 4];
    } else {
#pragma unroll
        for (int j = 0; j < 8; ++j) v[j] = 0.f;
    }
    unsigned int hh[4], lo[4];
#pragma unroll
    for (int p = 0; p < 4; ++p) {
        unsigned short h0 = f2bf(v[2 * p]), h1 = f2bf(v[2 * p + 1]);
        hh[p] = (unsigned int)h0 | ((unsigned int)h1 << 16);
        unsigned short l0 = f2bf(v[2 * p] - bfu2f(h0));
        unsigned short l1 = f2bf(v[2 * p + 1] - bfu2f(h1));
        lo[p] = (unsigned int)l0 | ((unsigned int)l1 << 16);
    }
    size_t o = ((size_t)n16 * 16 + k32) * 512 + l * 8;
    *(uint4*)&Ph[o] = make_uint4(hh[0], hh[1], hh[2], hh[3]);
    *(uint4*)&Pl[o] = make_uint4(lo[0], lo[1], lo[2], lo[3]);
}

// ---------------------------------------------------------------------------
// Pack W (f32 [512][32000], k-major) -> fragment-block bf16 hi/lo (n as m).
// ---------------------------------------------------------------------------
__global__ __launch_bounds__(256) void k_packW(
    const float* __restrict__ W,
    ushort_t* __restrict__ Ph, ushort_t* __restrict__ Pl)
{
    int c = blockIdx.x * 256 + threadIdx.x;
    int n16 = c >> 10, rem = c & 1023, k32 = rem >> 6, l = rem & 63;
    int n = n16 * 16 + (l & 15);
    int k = k32 * 32 + (l >> 4) * 8;
    float v[8];
#pragma unroll
    for (int j = 0; j < 8; ++j) v[j] = W[(size_t)(k + j) * V + n];
    unsigned int hh[4], lo[4];
#pragma unroll
    for (int p = 0; p < 4; ++p) {
        unsigned short h0 = f2bf(v[2 * p]), h1 = f2bf(v[2 * p + 1]);
        hh[p] = (unsigned int)h0 | ((unsigned int)h1 << 16);
        unsigned short l0 = f2bf(v[2 * p] - bfu2f(h0));
        unsigned short l1 = f2bf(v[2 * p + 1] - bfu2f(h1));
        lo[p] = (unsigned int)l0 | ((unsigned int)l1 << 16);
    }
    size_t o = ((size_t)n16 * 16 + k32) * 512 + l * 8;
    *(uint4*)&Ph[o] = make_uint4(hh[0], hh[1], hh[2], hh[3]);
    *(uint4*)&Pl[o] = make_uint4(lo[0], lo[1], lo[2], lo[3]);
}

// ---------------------------------------------------------------------------
// Kernel 2: split-bf16 MFMA GEMM, 256x256 tile, 8 waves, counted-vmcnt
// 2-deep gl16 pipeline (exact round-8 structure) — now TEMPLATED BY MODE
// FOR ABLATION:
//   MODE 0: full pipeline (the real computation, unchanged from r8)
//   MODE 1: STAGE-ONLY — all gl16 + counted vmcnt + both barriers per chunk,
//           ds_read/MFMA skipped. Measures the staging path in isolation.
//   MODE 2: MFMA-ONLY — all ds_read + 96 MFMA + both barriers per chunk on
//           (uninitialized) LDS, zero VMEM. Measures compute+lockstep alone.
//
// Rationale: 8 structural variants over 9 rounds are time-invariant at
// ~830us profiled (r9's layout change: WORSE). Models keep dying; per the
// skill's ablation rule, this round MEASURES the staging/compute split
// directly. Ablation dispatches run AFTER all real outputs, full tgt-size
// grid, writing to the then-dead pM1a scratch, so they appear in the top-5
// dispatch table next to the real GEMMs.
//
// Pre-committed read: stage-only ~= full & mfma-only small -> staging-
// serialized; mfma-only also large -> barrier/lockstep cost; both small ->
// overlap loss. Next round branches on this.
// ---------------------------------------------------------------------------
template<int MODE, bool TOP2>
__global__ __launch_bounds__(512, 2) void k_gemm(
    int nrb,
    const ushort_t* __restrict__ Ah, const ushort_t* __restrict__ Al,
    const ushort_t* __restrict__ Bh, const ushort_t* __restrict__ Bl,
    const float* __restrict__ bias,
    float* __restrict__ pL,
    float* __restrict__ pM1, float* __restrict__ pM2,
    int* __restrict__ pI1, int* __restrict__ pI2)
{
    // ---- XCD-aware block remap: rb-halves x vb-quarters (125 = 32+31+31+31)
    const int id  = blockIdx.x;
    const int xcd = id & 7;
    const int seq = id >> 3;
    const int rbg = xcd >> 2;
    const int vbg = xcd & 3;
    const int g0  = (nrb + 1) >> 1;
    const int nrbg = rbg ? (nrb - g0) : g0;
    const int vbl = seq / nrbg;
    const int rbl = seq - vbl * nrbg;
    const int vbsz = (vbg == 0) ? 32 : 31;
    if (vbl >= vbsz) return;
    const int rb = rbg ? (g0 + rbl) : rbl;
    const int vb = ((vbg == 0) ? 0 : (1 + 31 * vbg)) + vbl;   // bases 0,32,63,94

    // 2 buffers x 4 arrays x 16 KB = 128 KB
    __shared__ __attribute__((aligned(16))) ushort_t AshB[2][16 * 512];
    __shared__ __attribute__((aligned(16))) ushort_t AslB[2][16 * 512];
    __shared__ __attribute__((aligned(16))) ushort_t BshB[2][16 * 512];
    __shared__ __attribute__((aligned(16))) ushort_t BslB[2][16 * 512];
    __shared__ float sc_s[256][4];
    __shared__ float sc_m1[256][4], sc_m2[256][4];
    __shared__ int   sc_c1[256][4], sc_c2[256][4];

    const int tid = threadIdx.x;
    const int lane = tid & 63, w = tid >> 6;
    const int wy = w >> 2, wx = w & 3;     // wave grid 2x4, each wave 128x64

    f32x4 acc[8][4];
#pragma unroll
    for (int i = 0; i < 8; ++i)
#pragma unroll
        for (int j = 0; j < 4; ++j)
#pragma unroll
            for (int r = 0; r < 4; ++r) acc[i][j][r] = 0.f;

    // staging: wave pair (w>>1) owns one array; halves by (w&1). 8 gl16/wave.
    const ushort_t* gsrc = (w < 2) ? Ah : (w < 4) ? Al : (w < 6) ? Bh : Bl;
    ushort_t* base0 = (w < 2) ? AshB[0] : (w < 4) ? AslB[0] : (w < 6) ? BshB[0] : BslB[0];
    ushort_t* base1 = (w < 2) ? AshB[1] : (w < 4) ? AslB[1] : (w < 6) ? BshB[1] : BslB[1];
    const int half = (w & 1) * 8;
    ushort_t* ldb0 = base0 + half * 512;
    ushort_t* ldb1 = base1 + half * 512;
    const size_t n16base = (size_t)(((w < 4) ? rb : vb) * 16 + half);

#define STAGE(DST, IT)                                                   \
    _Pragma("unroll")                                                    \
    for (int mb = 0; mb < 8; ++mb)                                       \
        gl16(gsrc + (((n16base + mb) * 16 + (size_t)(IT)) << 9) + lane * 8, \
             (DST) + mb * 512);

// WIMM: 0x0F78 = vmcnt(8) (next chunk's 8 gl16 stay in flight),
//       0x0F70 = vmcnt(0) (final drain).  expcnt/lgkmcnt = no-wait.
#define STEPX(BUF, IT, DOPREF, WIMM)                                     \
{                                                                        \
    if (MODE != 2) __builtin_amdgcn_s_waitcnt(WIMM);                     \
    __builtin_amdgcn_s_barrier();        /* all waves' chunk IT ready */ \
    __builtin_amdgcn_sched_barrier(0);                                   \
    if (MODE != 1) {                                                     \
        const ushort_t* cAh = AshB[BUF];                                 \
        const ushort_t* cAl = AslB[BUF];                                 \
        const ushort_t* cBh = BshB[BUF];                                 \
        const ushort_t* cBl = BslB[BUF];                                 \
        short8 bhf[4], blf[4];                                           \
        _Pragma("unroll")                                                \
        for (int j = 0; j < 4; ++j) {                                    \
            bhf[j] = *(const short8*)&cBh[((wx * 4 + j) << 9) + (lane << 3)]; \
            blf[j] = *(const short8*)&cBl[((wx * 4 + j) << 9) + (lane << 3)]; \
        }                                                                \
        _Pragma("unroll")                                                \
        for (int i = 0; i < 8; ++i) {                                    \
            short8 ah = *(const short8*)&cAh[((wy * 8 + i) << 9) + (lane << 3)]; \
            short8 al = *(const short8*)&cAl[((wy * 8 + i) << 9) + (lane << 3)]; \
            _Pragma("unroll")                                            \
            for (int j = 0; j < 4; ++j) {                                \
                acc[i][j] = __builtin_amdgcn_mfma_f32_16x16x32_bf16(ah, bhf[j], acc[i][j], 0, 0, 0); \
                acc[i][j] = __builtin_amdgcn_mfma_f32_16x16x32_bf16(ah, blf[j], acc[i][j], 0, 0, 0); \
                acc[i][j] = __builtin_amdgcn_mfma_f32_16x16x32_bf16(al, bhf[j], acc[i][j], 0, 0, 0); \
            }                                                            \
        }                                                                \
    }                                                                    \
    __builtin_amdgcn_sched_barrier(0);                                   \
    __builtin_amdgcn_s_barrier();        /* all done reading buf BUF */  \
    if (MODE != 2 && (DOPREF)) { STAGE((BUF) ? ldb1 : ldb0, (IT) + 2) }  \
}

    // prologue: chunks 0,1 in flight (no drain)
    if (MODE != 2) {
        STAGE(ldb0, 0)
        STAGE(ldb1, 1)
    }

#pragma unroll 1
    for (int it = 0; it < 14; it += 2) {
        STEPX(0, it,     1, 0x0F78)      // consume even chunk, issue it+2
        STEPX(1, it + 1, 1, 0x0F78)      // consume odd chunk,  issue it+3
    }
    STEPX(0, 14, 0, 0x0F78)              // c15 still in flight
    STEPX(1, 15, 0, 0x0F70)              // final drain
#undef STAGE
#undef STEPX

    // ---- epilogue: sumexp (+ top-2) per row; emit per-128-col blocks ----
    // C/D layout (16x16x32): col = lane&15, row = (lane>>4)*4 + reg.
    float b4[4];
#pragma unroll
    for (int j = 0; j < 4; ++j) b4[j] = bias[vb * 256 + wx * 64 + j * 16 + (lane & 15)];
    const int colbase = vb * 256 + wx * 64 + (lane & 15);

#pragma unroll
    for (int i = 0; i < 8; ++i) {
#pragma unroll
        for (int r = 0; r < 4; ++r) {
            float s = 0.f;
            float m1 = -3e38f, m2 = -3e38f; int c1 = 0x7fffffff, c2 = 0x7fffffff;
#pragma unroll
            for (int j = 0; j < 4; ++j) {
                float v = acc[i][j][r] + b4[j];
                s += __expf(v);
                if (TOP2) t2_insert(m1, c1, m2, c2, v, colbase + j * 16);
            }
            for (int st = 1; st < 16; st <<= 1) {
                s += __shfl_xor(s, st, 64);
                if (TOP2) {
                    float om1 = __shfl_xor(m1, st, 64); int oc1 = __shfl_xor(c1, st, 64);
                    float om2 = __shfl_xor(m2, st, 64); int oc2 = __shfl_xor(c2, st, 64);
                    t2_insert(m1, c1, m2, c2, om1, oc1);
                    t2_insert(m1, c1, m2, c2, om2, oc2);
                }
            }
            if ((lane & 15) == 0) {
                int rowLoc = wy * 128 + i * 16 + (lane >> 4) * 4 + r;
                sc_s[rowLoc][wx] = s;
                if (TOP2) {
                    sc_m1[rowLoc][wx] = m1; sc_c1[rowLoc][wx] = c1;
                    sc_m2[rowLoc][wx] = m2; sc_c2[rowLoc][wx] = c2;
                }
            }
        }
    }
    __syncthreads();
    if (tid < 256) {
        int rowG = rb * 256 + tid;
        // col-halves {wx 0,1} -> vb*2, {wx 2,3} -> vb*2+1 (128 cols each)
        pL[(size_t)rowG * NVB + vb * 2 + 0] = sc_s[tid][0] + sc_s[tid][1];
        pL[(size_t)rowG * NVB + vb * 2 + 1] = sc_s[tid][2] + sc_s[tid][3];
        if (TOP2) {
#pragma unroll
            for (int h = 0; h < 2; ++h) {
                int g0i = h * 2, g1i = h * 2 + 1;
                float m1 = sc_m1[tid][g0i]; int c1 = sc_c1[tid][g0i];
                float m2 = sc_m2[tid][g0i]; int c2 = sc_c2[tid][g0i];
                t2_insert(m1, c1, m2, c2, sc_m1[tid][g1i], sc_c1[tid][g1i]);
                t2_insert(m1, c1, m2, c2, sc_m2[tid][g1i], sc_c2[tid][g1i]);
                pM1[(size_t)rowG * NVB + vb * 2 + h] = m1;
                pM2[(size_t)rowG * NVB + vb * 2 + h] = m2;
                pI1[(size_t)rowG * NVB + vb * 2 + h] = c1;
                pI2[(size_t)rowG * NVB + vb * 2 + h] = c2;
            }
        }
    }
}

// ---------------------------------------------------------------------------
// Kernel 3a: combine source partials -> L (denominator only)
// ---------------------------------------------------------------------------
__global__ __launch_bounds__(256) void k_combine_src(
    const float* __restrict__ pL, int nrows, float* __restrict__ L)
{
    int w = threadIdx.x >> 6, ll = threadIdx.x & 63;
    int row = blockIdx.x * 4 + w;
    if (row >= nrows) return;
    const float* p = &pL[(size_t)row * NVB];
    float s = 0.f;
    for (int vb = ll; vb < NVB; vb += 64) s += p[vb];
    for (int st = 1; st < 64; st <<= 1) s += __shfl_xor(s, st, 64);
    if (ll == 0) L[row] = s;
}

// ---------------------------------------------------------------------------
// Kernel 3b: combine target partials -> L + global approx top-2 candidates
// ---------------------------------------------------------------------------
__global__ __launch_bounds__(256) void k_combine_tgt(
    const float* __restrict__ pL,
    const float* __restrict__ pM1, const float* __restrict__ pM2,
    const int* __restrict__ pI1, const int* __restrict__ pI2,
    float* __restrict__ L, int* __restrict__ C0, int* __restrict__ C1)
{
    int w = threadIdx.x >> 6, ll = threadIdx.x & 63;
    int row = blockIdx.x * 4 + w;
    if (row >= 2048) return;
    size_t base = (size_t)row * NVB;
    float s = 0.f;
    float m1 = -3e38f, m2 = -3e38f; int c1 = 0x7fffffff, c2 = 0x7fffffff;
    for (int vb = ll; vb < NVB; vb += 64) {
        s += pL[base + vb];
        t2_insert(m1, c1, m2, c2, pM1[base + vb], pI1[base + vb]);
        t2_insert(m1, c1, m2, c2, pM2[base + vb], pI2[base + vb]);
    }
    for (int st = 1; st < 64; st <<= 1) {
        s += __shfl_xor(s, st, 64);
        float om1 = __shfl_xor(m1, st, 64); int oc1 = __shfl_xor(c1, st, 64);
        float om2 = __shfl_xor(m2, st, 64); int oc2 = __shfl_xor(c2, st, 64);
        t2_insert(m1, c1, m2, c2, om1, oc1);
        t2_insert(m1, c1, m2, c2, om2, oc2);
    }
    if (ll == 0) { L[row] = s; C0[row] = c1; C1[row] = c2; }
}

// ---------------------------------------------------------------------------
// Kernel 4: emission output (exact f32 dot for gathered columns)
// ---------------------------------------------------------------------------
__global__ __launch_bounds__(256) void k_emission(
    const float* __restrict__ ts, const float* __restrict__ W_sv,
    const float* __restrict__ b_sv, const int* __restrict__ sources,
    const float* __restrict__ L, float* __restrict__ out)
{
    __shared__ float wcol[H];
    __shared__ float sbias;
    int b = blockIdx.y, tx = blockIdx.x;
    int tid = threadIdx.x;
    int s = sources[b * 64 + tx];
    wcol[tid]       = W_sv[(size_t)tid * V + s];
    wcol[tid + 256] = W_sv[(size_t)(tid + 256) * V + s];
    if (tid == 0) sbias = b_sv[s];
    __syncthreads();
    int w = tid >> 6, ll = tid & 63;
    for (int r = w; r <= 64; r += 4) {
        int row = (r < 64) ? (b * 64 + r) : 2048;
        const float* a = &ts[(size_t)row * H];
        float sum = 0.f;
#pragma unroll
        for (int j = 0; j < 8; ++j) sum += a[ll * 8 + j] * wcol[ll * 8 + j];
        for (int m2 = 1; m2 < 64; m2 <<= 1) sum += __shfl_xor(sum, m2, 64);
        float prob = __expf(sum + sbias) / L[row];
        if (r < 64) {
            if (ll == 0) out[b * 8192 + r * 64 + tx] = prob;
        } else {
            out[b * 8192 + (64 + ll) * 64 + tx] = prob;
        }
    }
}

// ---------------------------------------------------------------------------
// Kernel 5: target epilogue — exact recompute of token + 2 argmax candidates
// ---------------------------------------------------------------------------
__global__ __launch_bounds__(256) void k_target_final(
    const float* __restrict__ tstate,
    const float* __restrict__ W_tv, const float* __restrict__ b_tv,
    const int* __restrict__ targets, const int* __restrict__ tlen,
    const float* __restrict__ L, const int* __restrict__ C0,
    const int* __restrict__ C1,
    float* __restrict__ out_exp, float* __restrict__ out_log,
    float* __restrict__ out_pred)
{
    int w = threadIdx.x >> 6, ll = threadIdx.x & 63;
    int row = blockIdx.x * 4 + w;
    if (row >= 2048) return;
    int tok = targets[row], a0 = C0[row], a1 = C1[row];
    const float* a = &tstate[(size_t)row * H];
    float s0 = 0.f, s1 = 0.f, s2 = 0.f;
#pragma unroll
    for (int j = 0; j < 8; ++j) {
        int k = ll * 8 + j;
        float av = a[k];
        const float* wr = &W_tv[(size_t)k * V];
        s0 += av * wr[tok]; s1 += av * wr[a0]; s2 += av * wr[a1];
    }
    for (int st = 1; st < 64; st <<= 1) {
        s0 += __shfl_xor(s0, st, 64);
        s1 += __shfl_xor(s1, st, 64);
        s2 += __shfl_xor(s2, st, 64);
    }
    if (ll == 0) {
        float ltok = s0 + b_tv[tok];
        float v0 = s1 + b_tv[a0], v1 = s2 + b_tv[a1];
        int pred = (v1 > v0 || (v1 == v0 && a1 < a0)) ? a1 : a0;
        float Li = L[row];
        int bb = row >> 6, t = row & 63;
        int mask = (t < tlen[bb]) ? 1 : 0;
        float prob = __expf(ltok) / Li;
        out_exp[row]  = mask ? prob : 0.f;
        out_log[row]  = mask ? (ltok - __logf(Li)) : 0.f;
        out_pred[row] = (float)pred;
    }
}

// ---------------------------------------------------------------------------
extern "C" void kernel_launch(void* const* d_in, const int* in_sizes, int n_in,
                              void* d_out, int out_size, void* d_ws, size_t ws_size,
                              hipStream_t stream)
{
    const float* y_hidden = (const float*)d_in[0];
    const float* y_null   = (const float*)d_in[1];
    const float* tstate   = (const float*)d_in[2];
    const float* W_em     = (const float*)d_in[3];
    const float* b_em     = (const float*)d_in[4];
    const float* W_sv     = (const float*)d_in[5];
    const float* b_sv     = (const float*)d_in[6];
    const float* W_tv     = (const float*)d_in[7];
    const float* b_tv     = (const float*)d_in[8];
    const int*   sources  = (const int*)d_in[9];
    const int*   targets  = (const int*)d_in[10];
    const int*   tlen     = (const int*)d_in[11];

    float* out = (float*)d_out;
    float* out_em   = out;
    float* out_exp  = out + 262144;
    float* out_log  = out + 264192;
    float* out_pred = out + 266240;

    // ---- workspace layout (float units) ----
    float* ws = (float*)d_ws;
    size_t off = 0;
    float*    ts    = ws + off; off += (size_t)2176 * H;
    ushort_t* tsPh  = (ushort_t*)(ws + off); off += (size_t)2304 * H / 2;  // 144 n16-blocks
    ushort_t* tsPl  = (ushort_t*)(ws + off); off += (size_t)2304 * H / 2;
    ushort_t* ttPh  = (ushort_t*)(ws + off); off += (size_t)2048 * H / 2;
    ushort_t* ttPl  = (ushort_t*)(ws + off); off += (size_t)2048 * H / 2;
    ushort_t* Wh    = (ushort_t*)(ws + off); off += (size_t)V * H / 2;   // reused
    ushort_t* Wl    = (ushort_t*)(ws + off); off += (size_t)V * H / 2;
    float* pL0  = ws + off; off += (size_t)2304 * NVB;
    float* pL1  = ws + off; off += (size_t)2048 * NVB;
    float* pM1a = ws + off; off += (size_t)2048 * NVB;
    float* pM1b = ws + off; off += (size_t)2048 * NVB;
    int*   pI1a = (int*)(ws + off); off += (size_t)2048 * NVB;
    int*   pI1b = (int*)(ws + off); off += (size_t)2048 * NVB;
    float* L0   = ws + off; off += 2176;
    float* L1   = ws + off; off += 2048;
    int*   C0   = (int*)(ws + off); off += 2048;
    int*   C1   = (int*)(ws + off); off += 2048;

    // 1) hidden-state transform
    k_emstate<<<dim3(8, 33), 256, 0, stream>>>(y_hidden, y_null, W_em, b_em, ts);

    // 1b) pack A-side operands into fragment-block bf16 hi/lo
    k_packA<<<(144 * 1024) / 256, 256, 0, stream>>>(ts, 2049, 144, tsPh, tsPl);
    k_packA<<<(128 * 1024) / 256, 256, 0, stream>>>(tstate, 2048, 128, ttPh, ttPl);

    // 2a) source side: pack W_sv, GEMM (256x256 tiles; nrb=9 -> halves 5/4)
    k_packW<<<(2000 * 1024) / 256, 256, 0, stream>>>(W_sv, Wh, Wl);
    k_gemm<0, false><<<dim3(8 * 160), 512, 0, stream>>>(
        9, tsPh, tsPl, Wh, Wl, b_sv, pL0, nullptr, nullptr, nullptr, nullptr);

    // 2b) target side: pack W_tv (buffer reuse, stream-ordered), GEMM
    k_packW<<<(2000 * 1024) / 256, 256, 0, stream>>>(W_tv, Wh, Wl);
    k_gemm<0, true><<<dim3(8 * 128), 512, 0, stream>>>(
        8, ttPh, ttPl, Wh, Wl, b_tv, pL1, pM1a, pM1b, pI1a, pI1b);

    // 3) combine partials
    k_combine_src<<<(2049 + 3) / 4, 256, 0, stream>>>(pL0, 2049, L0);
    k_combine_tgt<<<2048 / 4, 256, 0, stream>>>(pL1, pM1a, pM1b, pI1a, pI1b,
                                                L1, C0, C1);

    // 4) emission gather (exact f32 logits)
    k_emission<<<dim3(64, 32), 256, 0, stream>>>(ts, W_sv, b_sv, sources, L0, out_em);

    // 5) target epilogue with exact candidate recompute
    k_target_final<<<2048 / 4, 256, 0, stream>>>(tstate, W_tv, b_tv, targets, tlen,
                                                 L1, C0, C1,
                                                 out_exp, out_log, out_pred);

    // ---- 6) ABLATION DISPATCHES (diagnostic; outputs -> dead pM1a scratch)
    // pM1a/pM1b/pI1a/pI1b are dead after k_combine_tgt; Wh/Wl still hold
    // W_tv-packed; ttPh/ttPl alive. Same grid/shape as the real tgt GEMM so
    // durations are directly comparable in the dispatch table.
    // 6a) stage-only: full gl16+vmcnt+barrier lockstep, no ds_read/MFMA.
    k_gemm<1, false><<<dim3(8 * 128), 512, 0, stream>>>(
        8, ttPh, ttPl, Wh, Wl, b_tv, pM1a, nullptr, nullptr, nullptr, nullptr);
    // 6b) mfma-only: full ds_read+MFMA+barrier lockstep, zero VMEM.
    k_gemm<2, false><<<dim3(8 * 128), 512, 0, stream>>>(
        8, ttPh, ttPl, Wh, Wl, b_tv, pM1a, nullptr, nullptr, nullptr, nullptr);
}

// Round 11
// 1215.445 us; speedup vs baseline: 1.3850x; 1.2451x over previous
//
#include <hip/hip_runtime.h>
#include <math.h>

#define H 512
#define V 32000
#define NVB 250     // vocab blocks (32000 / 128)

typedef unsigned short ushort_t;
typedef __attribute__((ext_vector_type(8))) short short8;
typedef __attribute__((ext_vector_type(4))) float f32x4;

// ---- bf16 split helpers (bit-level RNE) ----
__device__ __forceinline__ unsigned short f2bf(float x) {
    unsigned int u; __builtin_memcpy(&u, &x, 4);
    unsigned int r = (u + 0x7fffu + ((u >> 16) & 1u)) >> 16;
    return (unsigned short)r;
}
__device__ __forceinline__ float bfu2f(unsigned short h) {
    unsigned int u = ((unsigned int)h) << 16;
    float f; __builtin_memcpy(&f, &u, 4);
    return f;
}

__device__ __forceinline__ void t2_insert(float& m1, int& c1, float& m2, int& c2,
                                          float v, int idx) {
    if (v > m1 || (v == m1 && idx < c1)) { m2 = m1; c2 = c1; m1 = v; c1 = idx; }
    else if (v > m2 || (v == m2 && idx < c2)) { m2 = v; c2 = idx; }
}

// async global->LDS, 16 bytes/lane; LDS dest = wave-uniform base + lane*16
__device__ __forceinline__ void gl16(const void* g, void* l) {
    __builtin_amdgcn_global_load_lds(
        (const __attribute__((address_space(1))) void*)g,
        (__attribute__((address_space(3))) void*)l,
        16, 0, 0);
}

// ---------------------------------------------------------------------------
// Kernel 1: ts = tanh(A @ W_em + b_em)
// ---------------------------------------------------------------------------
__global__ __launch_bounds__(256) void k_emstate(
    const float* __restrict__ y_hidden, const float* __restrict__ y_null,
    const float* __restrict__ W, const float* __restrict__ bias,
    float* __restrict__ ts)
{
    const int NR = 2049;
    __shared__ float As[16][64];
    __shared__ float Bs[16][64];
    int rb = blockIdx.y, cb = blockIdx.x;
    int row0 = rb * 64, col0 = cb * 64;
    int tid = threadIdx.x;
    int tr = tid >> 4, tc = tid & 15;
    float acc[4][4] = {};
    for (int k0 = 0; k0 < H; k0 += 16) {
        {
            int r = tid >> 2;
            int kk = (tid & 3) << 2;
            int row = row0 + r;
            float4 v = make_float4(0.f, 0.f, 0.f, 0.f);
            if (row < 2048)       v = *(const float4*)&y_hidden[row * H + k0 + kk];
            else if (row == 2048) v = *(const float4*)&y_null[k0 + kk];
            As[kk + 0][r] = v.x; As[kk + 1][r] = v.y;
            As[kk + 2][r] = v.z; As[kk + 3][r] = v.w;
            int bk = tid >> 4, bc = (tid & 15) << 2;
            *(float4*)&Bs[bk][bc] = *(const float4*)&W[(k0 + bk) * H + col0 + bc];
        }
        __syncthreads();
#pragma unroll
        for (int kk = 0; kk < 16; ++kk) {
            float4 a = *(float4*)&As[kk][tr * 4];
            float4 b = *(float4*)&Bs[kk][tc * 4];
            float av[4] = {a.x, a.y, a.z, a.w};
            float bv[4] = {b.x, b.y, b.z, b.w};
#pragma unroll
            for (int i = 0; i < 4; i++)
#pragma unroll
                for (int j = 0; j < 4; j++) acc[i][j] += av[i] * bv[j];
        }
        __syncthreads();
    }
#pragma unroll
    for (int i = 0; i < 4; i++) {
        int row = row0 + tr * 4 + i;
        if (row >= NR) break;
#pragma unroll
        for (int j = 0; j < 4; j++) {
            int col = col0 + tc * 4 + j;
            ts[(size_t)row * H + col] = tanhf(acc[i][j] + bias[col]);
        }
    }
}

// ---------------------------------------------------------------------------
// Pack A (f32 [rows][512]) -> fragment-block bf16 hi/lo.
// Block (n16,k32) = 1 KB at offset (n16*16+k32)*512 ushorts; lane l holds
// elems (m=n16*16+(l&15), k=k32*32+(l>>4)*8 .. +7), 16 B contiguous.
// ---------------------------------------------------------------------------
__global__ __launch_bounds__(256) void k_packA(
    const float* __restrict__ A, int nvalid, int nb16,
    ushort_t* __restrict__ Ph, ushort_t* __restrict__ Pl)
{
    int c = blockIdx.x * 256 + threadIdx.x;
    if (c >= nb16 * 1024) return;
    int n16 = c >> 10, rem = c & 1023, k32 = rem >> 6, l = rem & 63;
    int m = n16 * 16 + (l & 15);
    int k = k32 * 32 + (l >> 4) * 8;
    float v[8];
    if (m < nvalid) {
        *(float4*)&v[0] = *(const float4*)&A[(size_t)m * H + k];
        *(float4*)&v[4] = *(const float4*)&A[(size_t)m * H + k + 4];
    } else {
#pragma unroll
        for (int j = 0; j < 8; ++j) v[j] = 0.f;
    }
    unsigned int hh[4], lo[4];
#pragma unroll
    for (int p = 0; p < 4; ++p) {
        unsigned short h0 = f2bf(v[2 * p]), h1 = f2bf(v[2 * p + 1]);
        hh[p] = (unsigned int)h0 | ((unsigned int)h1 << 16);
        unsigned short l0 = f2bf(v[2 * p] - bfu2f(h0));
        unsigned short l1 = f2bf(v[2 * p + 1] - bfu2f(h1));
        lo[p] = (unsigned int)l0 | ((unsigned int)l1 << 16);
    }
    size_t o = ((size_t)n16 * 16 + k32) * 512 + l * 8;
    *(uint4*)&Ph[o] = make_uint4(hh[0], hh[1], hh[2], hh[3]);
    *(uint4*)&Pl[o] = make_uint4(lo[0], lo[1], lo[2], lo[3]);
}

// ---------------------------------------------------------------------------
// Pack W (f32 [512][32000], k-major) -> fragment-block bf16 hi/lo (n as m).
// ---------------------------------------------------------------------------
__global__ __launch_bounds__(256) void k_packW(
    const float* __restrict__ W,
    ushort_t* __restrict__ Ph, ushort_t* __restrict__ Pl)
{
    int c = blockIdx.x * 256 + threadIdx.x;
    int n16 = c >> 10, rem = c & 1023, k32 = rem >> 6, l = rem & 63;
    int n = n16 * 16 + (l & 15);
    int k = k32 * 32 + (l >> 4) * 8;
    float v[8];
#pragma unroll
    for (int j = 0; j < 8; ++j) v[j] = W[(size_t)(k + j) * V + n];
    unsigned int hh[4], lo[4];
#pragma unroll
    for (int p = 0; p < 4; ++p) {
        unsigned short h0 = f2bf(v[2 * p]), h1 = f2bf(v[2 * p + 1]);
        hh[p] = (unsigned int)h0 | ((unsigned int)h1 << 16);
        unsigned short l0 = f2bf(v[2 * p] - bfu2f(h0));
        unsigned short l1 = f2bf(v[2 * p + 1] - bfu2f(h1));
        lo[p] = (unsigned int)l0 | ((unsigned int)l1 << 16);
    }
    size_t o = ((size_t)n16 * 16 + k32) * 512 + l * 8;
    *(uint4*)&Ph[o] = make_uint4(hh[0], hh[1], hh[2], hh[3]);
    *(uint4*)&Pl[o] = make_uint4(lo[0], lo[1], lo[2], lo[3]);
}

// ---------------------------------------------------------------------------
// Kernel 2: split-bf16 MFMA GEMM, 128x128 tile, 4 waves, SINGLE-BUFFERED
// gl16 staging, 4 BLOCKS/CU (the m97 structure).
//
// Round-10 ablation verdict (wall-clock): stage-only + mfma-only dispatches
// at full grid cost only ~192us COMBINED, while the full pipeline runs
// ~450-550us per GEMM -> neither the staging path nor compute+barriers is
// the bottleneck in isolation; the INTERACTION (phases serialize, nothing
// fills the stalls) is. Root cause: every variant since r0 had <=8 waves/CU
// (r5+: ONE 148KB-LDS block/CU) -> when a block's waves sit in vmcnt/
// barrier, the CU idles. m97 (guide) runs the SAME drain-per-K-step shape
// at 874 TF with 3 blocks/CU: cross-block overlap (m114) fills the drains.
//
// Fix: slim the footprint to maximize resident blocks. 128^2 tile,
// single-buffer operands (4 x 8KB = 32KB) + 5KB scratch => ~37KB ->
// 4 blocks/CU via __launch_bounds__(256,4) (=4 blocks/CU for 256-thr
// blocks; caps VGPR at 128, r2 measured 88). 16 waves/CU in 4 INDEPENDENT
// barrier groups. Loop = m97's exact proven shape:
//   STAGE(it) -> vmcnt(0) -> barrier -> ds_read + 48 MFMA -> barrier.
// XCD remap and epilogue identical to the verified r2 kernel.
// ---------------------------------------------------------------------------
template<bool TOP2>
__global__ __launch_bounds__(256, 4) void k_gemm(
    int nrb,
    const ushort_t* __restrict__ Ah, const ushort_t* __restrict__ Al,
    const ushort_t* __restrict__ Bh, const ushort_t* __restrict__ Bl,
    const float* __restrict__ bias,
    float* __restrict__ pL,
    float* __restrict__ pM1, float* __restrict__ pM2,
    int* __restrict__ pI1, int* __restrict__ pI2)
{
    // ---- XCD-aware block remap (r2, verified bijective) ----
    const int id  = blockIdx.x;
    const int xcd = id & 7;          // HW round-robin XCD assignment
    const int seq = id >> 3;         // sequence within this XCD
    const int rbg = xcd >> 2;        // rb half: 0 or 1
    const int vbg = xcd & 3;         // vb quarter: 0..3
    const int g0  = (nrb + 1) >> 1;  // rows in half 0 (9 for 17, 8 for 16)
    const int nrbg = rbg ? (nrb - g0) : g0;
    const int vbl = seq / nrbg;      // vb-local (slow)
    const int rbl = seq - vbl * nrbg; // rb-local (fast: B-chunk reuse)
    const int vbsz = (vbg < 2) ? 63 : 62;
    if (vbl >= vbsz) return;
    const int rb = rbg ? (g0 + rbl) : rbl;
    const int vb = vbg * 63 - ((vbg == 3) ? 1 : 0) + vbl;  // bases 0,63,126,188

    // SINGLE buffer: 4 arrays x 8 KB = 32 KB (+ ~5 KB scratch)
    __shared__ __attribute__((aligned(16))) ushort_t Ash[8 * 512];
    __shared__ __attribute__((aligned(16))) ushort_t Asl[8 * 512];
    __shared__ __attribute__((aligned(16))) ushort_t Bsh[8 * 512];
    __shared__ __attribute__((aligned(16))) ushort_t Bsl[8 * 512];
    __shared__ float sc_s[128][2];
    __shared__ float sc_m1[128][2], sc_m2[128][2];
    __shared__ int   sc_c1[128][2], sc_c2[128][2];

    const int tid = threadIdx.x;
    const int row0 = rb * 128, col0 = vb * 128;
    const int lane = tid & 63, w = tid >> 6;
    const int wy = w >> 1, wx = w & 1;     // wave grid 2x2, each wave 64x64

    f32x4 acc[4][4];
#pragma unroll
    for (int i = 0; i < 4; ++i)
#pragma unroll
        for (int j = 0; j < 4; ++j)
#pragma unroll
            for (int r = 0; r < 4; ++r) acc[i][j][r] = 0.f;

    // staging: wave w stages one array (0:Ah 1:Al 2:Bh 3:Bl), 8 x 1 KB gl16.
    const ushort_t* gsrc = (w == 0) ? Ah : (w == 1) ? Al : (w == 2) ? Bh : Bl;
    ushort_t* ld = (w == 0) ? Ash : (w == 1) ? Asl : (w == 2) ? Bsh : Bsl;
    const int n16base = ((w < 2) ? row0 : col0) >> 4;

#pragma unroll 1
    for (int it = 0; it < 16; ++it) {
        // stage chunk it into the single buffer (wave-owned array)
#pragma unroll
        for (int mb = 0; mb < 8; ++mb)
            gl16(gsrc + (((size_t)(n16base + mb) * 16 + it) << 9) + lane * 8,
                 ld + mb * 512);
        __builtin_amdgcn_s_waitcnt(0x0F70);   // vmcnt(0): my DMA landed
        __builtin_amdgcn_s_barrier();         // all waves' chunk ready
        __builtin_amdgcn_sched_barrier(0);

        // LDS -> register fragments, then 48 MFMAs
        short8 ahf[4], alf[4], bhf[4], blf[4];
#pragma unroll
        for (int i = 0; i < 4; ++i) {
            ahf[i] = *(const short8*)&Ash[((wy * 4 + i) << 9) + (lane << 3)];
            alf[i] = *(const short8*)&Asl[((wy * 4 + i) << 9) + (lane << 3)];
            bhf[i] = *(const short8*)&Bsh[((wx * 4 + i) << 9) + (lane << 3)];
            blf[i] = *(const short8*)&Bsl[((wx * 4 + i) << 9) + (lane << 3)];
        }
#pragma unroll
        for (int i = 0; i < 4; ++i)
#pragma unroll
            for (int j = 0; j < 4; ++j) {
                acc[i][j] = __builtin_amdgcn_mfma_f32_16x16x32_bf16(ahf[i], bhf[j], acc[i][j], 0, 0, 0);
                acc[i][j] = __builtin_amdgcn_mfma_f32_16x16x32_bf16(ahf[i], blf[j], acc[i][j], 0, 0, 0);
                acc[i][j] = __builtin_amdgcn_mfma_f32_16x16x32_bf16(alf[i], bhf[j], acc[i][j], 0, 0, 0);
            }
        __builtin_amdgcn_sched_barrier(0);
        __builtin_amdgcn_s_barrier();         // all reads done; safe to overwrite
    }

    // ---- epilogue: shift-free sumexp (+ top-2) per row over 128 cols ----
    // C/D layout (16x16x32): col = lane&15, row = (lane>>4)*4 + reg.
    float b4[4];
#pragma unroll
    for (int j = 0; j < 4; ++j) b4[j] = bias[col0 + wx * 64 + j * 16 + (lane & 15)];
    const int colbase = col0 + wx * 64 + (lane & 15);

#pragma unroll
    for (int i = 0; i < 4; ++i) {
#pragma unroll
        for (int r = 0; r < 4; ++r) {
            float s = 0.f;
            float m1 = -3e38f, m2 = -3e38f; int c1 = 0x7fffffff, c2 = 0x7fffffff;
#pragma unroll
            for (int j = 0; j < 4; ++j) {
                float v = acc[i][j][r] + b4[j];
                s += __expf(v);
                if (TOP2) t2_insert(m1, c1, m2, c2, v, colbase + j * 16);
            }
            for (int st = 1; st < 16; st <<= 1) {
                s += __shfl_xor(s, st, 64);
                if (TOP2) {
                    float om1 = __shfl_xor(m1, st, 64); int oc1 = __shfl_xor(c1, st, 64);
                    float om2 = __shfl_xor(m2, st, 64); int oc2 = __shfl_xor(c2, st, 64);
                    t2_insert(m1, c1, m2, c2, om1, oc1);
                    t2_insert(m1, c1, m2, c2, om2, oc2);
                }
            }
            if ((lane & 15) == 0) {
                int rowLoc = wy * 64 + i * 16 + (lane >> 4) * 4 + r;
                sc_s[rowLoc][wx] = s;
                if (TOP2) {
                    sc_m1[rowLoc][wx] = m1; sc_c1[rowLoc][wx] = c1;
                    sc_m2[rowLoc][wx] = m2; sc_c2[rowLoc][wx] = c2;
                }
            }
        }
    }
    __syncthreads();
    if (tid < 128) {
        int rowG = row0 + tid;
        pL[(size_t)rowG * NVB + vb] = sc_s[tid][0] + sc_s[tid][1];
        if (TOP2) {
            float m1 = sc_m1[tid][0]; int c1 = sc_c1[tid][0];
            float m2 = sc_m2[tid][0]; int c2 = sc_c2[tid][0];
            t2_insert(m1, c1, m2, c2, sc_m1[tid][1], sc_c1[tid][1]);
            t2_insert(m1, c1, m2, c2, sc_m2[tid][1], sc_c2[tid][1]);
            pM1[(size_t)rowG * NVB + vb] = m1;
            pM2[(size_t)rowG * NVB + vb] = m2;
            pI1[(size_t)rowG * NVB + vb] = c1;
            pI2[(size_t)rowG * NVB + vb] = c2;
        }
    }
}

// ---------------------------------------------------------------------------
// Kernel 3a: combine source partials -> L (denominator only)
// ---------------------------------------------------------------------------
__global__ __launch_bounds__(256) void k_combine_src(
    const float* __restrict__ pL, int nrows, float* __restrict__ L)
{
    int w = threadIdx.x >> 6, ll = threadIdx.x & 63;
    int row = blockIdx.x * 4 + w;
    if (row >= nrows) return;
    const float* p = &pL[(size_t)row * NVB];
    float s = 0.f;
    for (int vb = ll; vb < NVB; vb += 64) s += p[vb];
    for (int st = 1; st < 64; st <<= 1) s += __shfl_xor(s, st, 64);
    if (ll == 0) L[row] = s;
}

// ---------------------------------------------------------------------------
// Kernel 3b: combine target partials -> L + global approx top-2 candidates
// ---------------------------------------------------------------------------
__global__ __launch_bounds__(256) void k_combine_tgt(
    const float* __restrict__ pL,
    const float* __restrict__ pM1, const float* __restrict__ pM2,
    const int* __restrict__ pI1, const int* __restrict__ pI2,
    float* __restrict__ L, int* __restrict__ C0, int* __restrict__ C1)
{
    int w = threadIdx.x >> 6, ll = threadIdx.x & 63;
    int row = blockIdx.x * 4 + w;
    if (row >= 2048) return;
    size_t base = (size_t)row * NVB;
    float s = 0.f;
    float m1 = -3e38f, m2 = -3e38f; int c1 = 0x7fffffff, c2 = 0x7fffffff;
    for (int vb = ll; vb < NVB; vb += 64) {
        s += pL[base + vb];
        t2_insert(m1, c1, m2, c2, pM1[base + vb], pI1[base + vb]);
        t2_insert(m1, c1, m2, c2, pM2[base + vb], pI2[base + vb]);
    }
    for (int st = 1; st < 64; st <<= 1) {
        s += __shfl_xor(s, st, 64);
        float om1 = __shfl_xor(m1, st, 64); int oc1 = __shfl_xor(c1, st, 64);
        float om2 = __shfl_xor(m2, st, 64); int oc2 = __shfl_xor(c2, st, 64);
        t2_insert(m1, c1, m2, c2, om1, oc1);
        t2_insert(m1, c1, m2, c2, om2, oc2);
    }
    if (ll == 0) { L[row] = s; C0[row] = c1; C1[row] = c2; }
}

// ---------------------------------------------------------------------------
// Kernel 4: emission output (exact f32 dot for gathered columns)
// ---------------------------------------------------------------------------
__global__ __launch_bounds__(256) void k_emission(
    const float* __restrict__ ts, const float* __restrict__ W_sv,
    const float* __restrict__ b_sv, const int* __restrict__ sources,
    const float* __restrict__ L, float* __restrict__ out)
{
    __shared__ float wcol[H];
    __shared__ float sbias;
    int b = blockIdx.y, tx = blockIdx.x;
    int tid = threadIdx.x;
    int s = sources[b * 64 + tx];
    wcol[tid]       = W_sv[(size_t)tid * V + s];
    wcol[tid + 256] = W_sv[(size_t)(tid + 256) * V + s];
    if (tid == 0) sbias = b_sv[s];
    __syncthreads();
    int w = tid >> 6, ll = tid & 63;
    for (int r = w; r <= 64; r += 4) {
        int row = (r < 64) ? (b * 64 + r) : 2048;
        const float* a = &ts[(size_t)row * H];
        float sum = 0.f;
#pragma unroll
        for (int j = 0; j < 8; ++j) sum += a[ll * 8 + j] * wcol[ll * 8 + j];
        for (int m2 = 1; m2 < 64; m2 <<= 1) sum += __shfl_xor(sum, m2, 64);
        float prob = __expf(sum + sbias) / L[row];
        if (r < 64) {
            if (ll == 0) out[b * 8192 + r * 64 + tx] = prob;
        } else {
            out[b * 8192 + (64 + ll) * 64 + tx] = prob;
        }
    }
}

// ---------------------------------------------------------------------------
// Kernel 5: target epilogue — exact recompute of token + 2 argmax candidates
// ---------------------------------------------------------------------------
__global__ __launch_bounds__(256) void k_target_final(
    const float* __restrict__ tstate,
    const float* __restrict__ W_tv, const float* __restrict__ b_tv,
    const int* __restrict__ targets, const int* __restrict__ tlen,
    const float* __restrict__ L, const int* __restrict__ C0,
    const int* __restrict__ C1,
    float* __restrict__ out_exp, float* __restrict__ out_log,
    float* __restrict__ out_pred)
{
    int w = threadIdx.x >> 6, ll = threadIdx.x & 63;
    int row = blockIdx.x * 4 + w;
    if (row >= 2048) return;
    int tok = targets[row], a0 = C0[row], a1 = C1[row];
    const float* a = &tstate[(size_t)row * H];
    float s0 = 0.f, s1 = 0.f, s2 = 0.f;
#pragma unroll
    for (int j = 0; j < 8; ++j) {
        int k = ll * 8 + j;
        float av = a[k];
        const float* wr = &W_tv[(size_t)k * V];
        s0 += av * wr[tok]; s1 += av * wr[a0]; s2 += av * wr[a1];
    }
    for (int st = 1; st < 64; st <<= 1) {
        s0 += __shfl_xor(s0, st, 64);
        s1 += __shfl_xor(s1, st, 64);
        s2 += __shfl_xor(s2, st, 64);
    }
    if (ll == 0) {
        float ltok = s0 + b_tv[tok];
        float v0 = s1 + b_tv[a0], v1 = s2 + b_tv[a1];
        int pred = (v1 > v0 || (v1 == v0 && a1 < a0)) ? a1 : a0;
        float Li = L[row];
        int bb = row >> 6, t = row & 63;
        int mask = (t < tlen[bb]) ? 1 : 0;
        float prob = __expf(ltok) / Li;
        out_exp[row]  = mask ? prob : 0.f;
        out_log[row]  = mask ? (ltok - __logf(Li)) : 0.f;
        out_pred[row] = (float)pred;
    }
}

// ---------------------------------------------------------------------------
extern "C" void kernel_launch(void* const* d_in, const int* in_sizes, int n_in,
                              void* d_out, int out_size, void* d_ws, size_t ws_size,
                              hipStream_t stream)
{
    const float* y_hidden = (const float*)d_in[0];
    const float* y_null   = (const float*)d_in[1];
    const float* tstate   = (const float*)d_in[2];
    const float* W_em     = (const float*)d_in[3];
    const float* b_em     = (const float*)d_in[4];
    const float* W_sv     = (const float*)d_in[5];
    const float* b_sv     = (const float*)d_in[6];
    const float* W_tv     = (const float*)d_in[7];
    const float* b_tv     = (const float*)d_in[8];
    const int*   sources  = (const int*)d_in[9];
    const int*   targets  = (const int*)d_in[10];
    const int*   tlen     = (const int*)d_in[11];

    float* out = (float*)d_out;
    float* out_em   = out;
    float* out_exp  = out + 262144;
    float* out_log  = out + 264192;
    float* out_pred = out + 266240;

    // ---- workspace layout (float units) ----
    float* ws = (float*)d_ws;
    size_t off = 0;
    float*    ts    = ws + off; off += (size_t)2176 * H;
    ushort_t* tsPh  = (ushort_t*)(ws + off); off += (size_t)2176 * H / 2;
    ushort_t* tsPl  = (ushort_t*)(ws + off); off += (size_t)2176 * H / 2;
    ushort_t* ttPh  = (ushort_t*)(ws + off); off += (size_t)2048 * H / 2;
    ushort_t* ttPl  = (ushort_t*)(ws + off); off += (size_t)2048 * H / 2;
    ushort_t* Wh    = (ushort_t*)(ws + off); off += (size_t)V * H / 2;   // reused
    ushort_t* Wl    = (ushort_t*)(ws + off); off += (size_t)V * H / 2;
    float* pL0  = ws + off; off += (size_t)2176 * NVB;
    float* pL1  = ws + off; off += (size_t)2048 * NVB;
    float* pM1a = ws + off; off += (size_t)2048 * NVB;
    float* pM1b = ws + off; off += (size_t)2048 * NVB;
    int*   pI1a = (int*)(ws + off); off += (size_t)2048 * NVB;
    int*   pI1b = (int*)(ws + off); off += (size_t)2048 * NVB;
    float* L0   = ws + off; off += 2176;
    float* L1   = ws + off; off += 2048;
    int*   C0   = (int*)(ws + off); off += 2048;
    int*   C1   = (int*)(ws + off); off += 2048;

    // 1) hidden-state transform
    k_emstate<<<dim3(8, 33), 256, 0, stream>>>(y_hidden, y_null, W_em, b_em, ts);

    // 1b) pack A-side operands into fragment-block bf16 hi/lo (136/128 blocks)
    k_packA<<<(136 * 1024) / 256, 256, 0, stream>>>(ts, 2049, 136, tsPh, tsPl);
    k_packA<<<(128 * 1024) / 256, 256, 0, stream>>>(tstate, 2048, 128, ttPh, ttPl);

    // 2a) source side: pack W_sv, GEMM (XCD-partitioned grid:
    //     nrb=17 -> halves 9/8; max per-XCD count = 9*63 = 567 -> 8*567 blocks)
    k_packW<<<(2000 * 1024) / 256, 256, 0, stream>>>(W_sv, Wh, Wl);
    k_gemm<false><<<dim3(8 * 567), 256, 0, stream>>>(
        17, tsPh, tsPl, Wh, Wl, b_sv, pL0, nullptr, nullptr, nullptr, nullptr);

    // 2b) target side: pack W_tv (buffer reuse, stream-ordered), GEMM
    //     nrb=16 -> halves 8/8; max per-XCD count = 8*63 = 504 -> 8*504 blocks
    k_packW<<<(2000 * 1024) / 256, 256, 0, stream>>>(W_tv, Wh, Wl);
    k_gemm<true><<<dim3(8 * 504), 256, 0, stream>>>(
        16, ttPh, ttPl, Wh, Wl, b_tv, pL1, pM1a, pM1b, pI1a, pI1b);

    // 3) combine partials
    k_combine_src<<<(2049 + 3) / 4, 256, 0, stream>>>(pL0, 2049, L0);
    k_combine_tgt<<<2048 / 4, 256, 0, stream>>>(pL1, pM1a, pM1b, pI1a, pI1b,
                                                L1, C0, C1);

    // 4) emission gather (exact f32 logits)
    k_emission<<<dim3(64, 32), 256, 0, stream>>>(ts, W_sv, b_sv, sources, L0, out_em);

    // 5) target epilogue with exact candidate recompute
    k_target_final<<<2048 / 4, 256, 0, stream>>>(tstate, W_tv, b_tv, targets, tlen,
                                                 L1, C0, C1,
                                                 out_exp, out_log, out_pred);
}